// Round 9
// baseline (689.189 us; speedup 1.0000x reference)
//
#include <hip/hip_runtime.h>
#include <hip/hip_fp16.h>

// TemporalGCN: 2x GCNConv(64->64) + relu, global_mean_pool(64 graphs), linear 64->64.
// R8: agg gathers 8-deep (64 rows in flight/wave); layer-2 agg fuses the
// global_mean_pool (register partials + native f32 global atomics; h2 for
// layer 2 is never materialized); part_kernel at 512 threads/block.
// Pipeline: part -> sort(+dinv) -> gemm1 -> agg1 -> gemm2 -> agg2+pool -> final.

#define DF 64
#define BSH 7                 // bucket = 128 consecutive dst nodes
#define BNODES 128
#define CAP 4096              // per-bucket edge capacity (mean 2048, >40 sigma)

struct alignas(8)  h4 { __half2 a, b; };        // 4 halves = 8B
struct alignas(16) h8 { __half2 a, b, c, d; };  // 8 halves = 16B

// ---------------- P1: partition edges into dst/128 buckets ----------------

__global__ __launch_bounds__(512) void part_kernel(
        const int* __restrict__ src, const int* __restrict__ dst,
        const int4* __restrict__ src4, const int4* __restrict__ dst4,
        int E, unsigned* __restrict__ bedges, int* __restrict__ bucketCur, int nb) {
    __shared__ int lcnt[1024];
    __shared__ int lbase[1024];
    int tid = threadIdx.x;
    for (int t = tid; t < nb; t += 512) lcnt[t] = 0;
    __syncthreads();
    int nq = E >> 2;
    unsigned packed[16];
    int bkt[16];
    int rk[16];
    int qbase = blockIdx.x * 2048;        // 2048 quads = 8192 edges / block
#pragma unroll
    for (int c = 0; c < 4; c++) {
        int qi = qbase + c * 512 + tid;
        int4 s = {0, 0, 0, 0}, d = {0, 0, 0, 0};
        bool v = qi < nq;
        if (v) { s = src4[qi]; d = dst4[qi]; }
        packed[4*c+0] = (unsigned)s.x | ((unsigned)(d.x & (BNODES-1)) << 24);
        packed[4*c+1] = (unsigned)s.y | ((unsigned)(d.y & (BNODES-1)) << 24);
        packed[4*c+2] = (unsigned)s.z | ((unsigned)(d.z & (BNODES-1)) << 24);
        packed[4*c+3] = (unsigned)s.w | ((unsigned)(d.w & (BNODES-1)) << 24);
        bkt[4*c+0] = v ? (d.x >> BSH) : -1;
        bkt[4*c+1] = v ? (d.y >> BSH) : -1;
        bkt[4*c+2] = v ? (d.z >> BSH) : -1;
        bkt[4*c+3] = v ? (d.w >> BSH) : -1;
    }
#pragma unroll
    for (int j = 0; j < 16; j++)
        rk[j] = (bkt[j] >= 0) ? atomicAdd(&lcnt[bkt[j]], 1) : 0;
    __syncthreads();
    for (int t = tid; t < nb; t += 512)
        lbase[t] = lcnt[t] ? atomicAdd(&bucketCur[t], lcnt[t]) : 0;
    __syncthreads();
#pragma unroll
    for (int j = 0; j < 16; j++) {
        if (bkt[j] >= 0) {
            int pos = lbase[bkt[j]] + rk[j];
            if (pos < CAP) bedges[(size_t)bkt[j] * CAP + pos] = packed[j];
        }
    }
    if (blockIdx.x == 0 && tid < (E & 3)) {
        int e = nq * 4 + tid;
        int sv = src[e], dv = dst[e];
        int b = dv >> BSH;
        int pos = atomicAdd(&bucketCur[b], 1);
        if (pos < CAP)
            bedges[(size_t)b * CAP + pos] =
                (unsigned)sv | ((unsigned)(dv & (BNODES-1)) << 24);
    }
}

__global__ void part_scalar_kernel(const int* __restrict__ src, const int* __restrict__ dst,
                                   int E, unsigned* __restrict__ bedges,
                                   int* __restrict__ bucketCur) {
    int stride = gridDim.x * blockDim.x;
    for (int e = blockIdx.x * blockDim.x + threadIdx.x; e < E; e += stride) {
        int sv = src[e], dv = dst[e];
        int b = dv >> BSH;
        int pos = atomicAdd(&bucketCur[b], 1);
        if (pos < CAP)
            bedges[(size_t)b * CAP + pos] =
                (unsigned)sv | ((unsigned)(dv & (BNODES-1)) << 24);
    }
}

// ------- P2: per-bucket LDS counting sort (int atomics only) + offsets + dinv -------

__global__ __launch_bounds__(256) void sort_kernel(
        unsigned* __restrict__ bedges, const int* __restrict__ bucketCur,
        int* __restrict__ offs, float* __restrict__ dinv, int N) {
    __shared__ unsigned ein[CAP];
    __shared__ unsigned eout[CAP];
    __shared__ int cnt[BNODES];
    __shared__ int sc[BNODES];
    __shared__ int off[BNODES + 1];
    __shared__ int cur[BNODES];
    int b = blockIdx.x, tid = threadIdx.x;
    int n = min(bucketCur[b], CAP);
    unsigned* gp = bedges + (size_t)b * CAP;
    if (tid < BNODES) cnt[tid] = 0;
    __syncthreads();
    for (int i = tid; i < n; i += 256) {
        unsigned u = gp[i];
        ein[i] = u;
        atomicAdd(&cnt[u >> 24], 1);      // native ds int atomic
    }
    __syncthreads();
    if (tid < BNODES) sc[tid] = cnt[tid];
    __syncthreads();
    for (int d = 1; d < BNODES; d <<= 1) {
        int v = (tid >= d && tid < BNODES) ? sc[tid - d] : 0;
        __syncthreads();
        if (tid < BNODES) sc[tid] += v;
        __syncthreads();
    }
    if (tid < BNODES) {
        off[tid + 1] = sc[tid];
        cur[tid] = sc[tid] - cnt[tid];
        if (tid == 0) off[0] = 0;
    }
    __syncthreads();
    for (int i = tid; i < n; i += 256) {
        unsigned u = ein[i];
        int p = atomicAdd(&cur[u >> 24], 1);
        eout[p] = u;
    }
    __syncthreads();
    for (int i = tid; i < n; i += 256) gp[i] = eout[i];
    if (tid <= BNODES) offs[(size_t)b * (BNODES + 1) + tid] = off[tid];
    int node = (b << BSH) + tid;
    if (tid < BNODES && node < N)
        dinv[node] = 1.0f / sqrtf((float)(cnt[tid] + 1));   // deg = in + self-loop
}

// ---------------- per-layer compute ----------------

// Y[row][c] = (sum_k X[row][k] * W[k][c]) * dinv[row]; f32 input -> fp16 out.
__global__ void gemm_f32in(const float4* __restrict__ X4, const float4* __restrict__ W4,
                           const float* __restrict__ dinv, h4* __restrict__ Y2, int n) {
    __shared__ float4 Wl4[64][16];   // [k][c4]
    __shared__ float Xl[16][68];     // padded: conflict-free broadcast
    int tid = threadIdx.x;
    float4* Wf = &Wl4[0][0];
#pragma unroll
    for (int i = 0; i < 4; i++) {
        int idx = tid + i * 256;     // idx = k*16 + c4
        Wf[idx] = W4[idx];
    }
    int row0 = blockIdx.x * 16;
    int r = tid >> 4, c4 = tid & 15;
    {
        int row = row0 + r;
        float4 v = (row < n) ? X4[(size_t)row * 16 + c4] : float4{0.f, 0.f, 0.f, 0.f};
        Xl[r][c4 * 4 + 0] = v.x;
        Xl[r][c4 * 4 + 1] = v.y;
        Xl[r][c4 * 4 + 2] = v.z;
        Xl[r][c4 * 4 + 3] = v.w;
    }
    __syncthreads();
    float ax = 0.f, ay = 0.f, az = 0.f, aw = 0.f;
#pragma unroll
    for (int k = 0; k < 64; k++) {
        float xv = Xl[r][k];
        float4 w = Wl4[k][c4];
        ax += xv * w.x;
        ay += xv * w.y;
        az += xv * w.z;
        aw += xv * w.w;
    }
    int row = row0 + r;
    if (row < n) {
        float dv = dinv[row];
        h4 o;
        o.a = __floats2half2_rn(ax * dv, ay * dv);
        o.b = __floats2half2_rn(az * dv, aw * dv);
        Y2[(size_t)row * 16 + c4] = o;
    }
}

// same, fp16 input (layer 2: X = h stored as fp16)
__global__ void gemm_f16in(const h4* __restrict__ X2, const float4* __restrict__ W4,
                           const float* __restrict__ dinv, h4* __restrict__ Y2, int n) {
    __shared__ float4 Wl4[64][16];
    __shared__ float Xl[16][68];
    int tid = threadIdx.x;
    float4* Wf = &Wl4[0][0];
#pragma unroll
    for (int i = 0; i < 4; i++) {
        int idx = tid + i * 256;
        Wf[idx] = W4[idx];
    }
    int row0 = blockIdx.x * 16;
    int r = tid >> 4, c4 = tid & 15;
    {
        int row = row0 + r;
        h4 hv = (row < n) ? X2[(size_t)row * 16 + c4] : h4{__half2{0, 0}, __half2{0, 0}};
        float2 va = __half22float2(hv.a), vb = __half22float2(hv.b);
        Xl[r][c4 * 4 + 0] = va.x;
        Xl[r][c4 * 4 + 1] = va.y;
        Xl[r][c4 * 4 + 2] = vb.x;
        Xl[r][c4 * 4 + 3] = vb.y;
    }
    __syncthreads();
    float ax = 0.f, ay = 0.f, az = 0.f, aw = 0.f;
#pragma unroll
    for (int k = 0; k < 64; k++) {
        float xv = Xl[r][k];
        float4 w = Wl4[k][c4];
        ax += xv * w.x;
        ay += xv * w.y;
        az += xv * w.z;
        aw += xv * w.w;
    }
    int row = row0 + r;
    if (row < n) {
        float dv = dinv[row];
        h4 o;
        o.a = __floats2half2_rn(ax * dv, ay * dv);
        o.b = __floats2half2_rn(az * dv, aw * dv);
        Y2[(size_t)row * 16 + c4] = o;
    }
}

#define ACC8(A, w)                                        \
    { float2 _p = __half22float2((w).a);                  \
      A[0] += _p.x; A[1] += _p.y;                         \
      _p = __half22float2((w).b);                         \
      A[2] += _p.x; A[3] += _p.y;                         \
      _p = __half22float2((w).c);                         \
      A[4] += _p.x; A[5] += _p.y;                         \
      _p = __half22float2((w).d);                         \
      A[6] += _p.x; A[7] += _p.y; }

// Shared edge-sum core: computes S[8] = sum over node's in-edges of y[src][q-slice].
#define EDGE_SUM(S_, s_, e_)                                                   \
    float A0[8], A1[8], A2[8], A3[8];                                          \
    _Pragma("unroll")                                                          \
    for (int j = 0; j < 8; j++) { A0[j] = 0.f; A1[j] = 0.f; A2[j] = 0.f; A3[j] = 0.f; } \
    {                                                                          \
        int i = (s_);                                                          \
        for (; i + 7 < (e_); i += 8) {                                         \
            unsigned u0 = eb[i],     u1 = eb[i + 1], u2 = eb[i + 2], u3 = eb[i + 3]; \
            unsigned u4 = eb[i + 4], u5 = eb[i + 5], u6 = eb[i + 6], u7 = eb[i + 7]; \
            h8 w0 = Y8[(size_t)(u0 & 0xFFFFFFu) * 8 + q];                      \
            h8 w1 = Y8[(size_t)(u1 & 0xFFFFFFu) * 8 + q];                      \
            h8 w2 = Y8[(size_t)(u2 & 0xFFFFFFu) * 8 + q];                      \
            h8 w3 = Y8[(size_t)(u3 & 0xFFFFFFu) * 8 + q];                      \
            h8 w4 = Y8[(size_t)(u4 & 0xFFFFFFu) * 8 + q];                      \
            h8 w5 = Y8[(size_t)(u5 & 0xFFFFFFu) * 8 + q];                      \
            h8 w6 = Y8[(size_t)(u6 & 0xFFFFFFu) * 8 + q];                      \
            h8 w7 = Y8[(size_t)(u7 & 0xFFFFFFu) * 8 + q];                      \
            ACC8(A0, w0); ACC8(A1, w1); ACC8(A2, w2); ACC8(A3, w3);            \
            ACC8(A0, w4); ACC8(A1, w5); ACC8(A2, w6); ACC8(A3, w7);            \
        }                                                                      \
        for (; i + 3 < (e_); i += 4) {                                         \
            unsigned u0 = eb[i], u1 = eb[i + 1], u2 = eb[i + 2], u3 = eb[i + 3]; \
            h8 w0 = Y8[(size_t)(u0 & 0xFFFFFFu) * 8 + q];                      \
            h8 w1 = Y8[(size_t)(u1 & 0xFFFFFFu) * 8 + q];                      \
            h8 w2 = Y8[(size_t)(u2 & 0xFFFFFFu) * 8 + q];                      \
            h8 w3 = Y8[(size_t)(u3 & 0xFFFFFFu) * 8 + q];                      \
            ACC8(A0, w0); ACC8(A1, w1); ACC8(A2, w2); ACC8(A3, w3);            \
        }                                                                      \
        for (; i < (e_); i++) {                                                \
            unsigned u = eb[i];                                                \
            h8 w = Y8[(size_t)(u & 0xFFFFFFu) * 8 + q];                        \
            ACC8(A0, w);                                                       \
        }                                                                      \
    }                                                                          \
    _Pragma("unroll")                                                          \
    for (int j = 0; j < 8; j++) S_[j] = A0[j] + A1[j] + A2[j] + A3[j];

// Layer-1 agg: H[node][:] = relu(dinv*(sum + y[node]) + b) -> fp16 store.
// One block per HALF bucket (64 nodes); 256 thr = 32 groups x 8 lanes, h8/lane.
__global__ __launch_bounds__(256) void agg_kernel(
        const h8* __restrict__ Y8, const unsigned* __restrict__ bedges,
        const int* __restrict__ offs, const float* __restrict__ dinv,
        const float* __restrict__ bias, h8* __restrict__ H8, int N) {
    __shared__ unsigned eb[CAP];
    __shared__ int off[65];
    int blk = blockIdx.x;
    int b = blk >> 1, half = blk & 1;
    int tid = threadIdx.x;
    if (tid < 65) off[tid] = offs[(size_t)b * (BNODES + 1) + half * 64 + tid];
    __syncthreads();
    int e0 = off[0];
    int ecnt = off[64] - e0;
    const unsigned* gp = bedges + (size_t)b * CAP + e0;
    for (int i = tid; i < ecnt; i += 256) eb[i] = gp[i];
    __syncthreads();
    int gg = tid >> 3, q = tid & 7;
    float bq[8];
#pragma unroll
    for (int j = 0; j < 8; j++) bq[j] = bias[q * 8 + j];
#pragma unroll
    for (int rr = 0; rr < 2; rr++) {
        int r = gg + rr * 32;
        int node = (b << BSH) + half * 64 + r;
        if (node >= N) continue;
        int s = off[r] - e0, e = off[r + 1] - e0;
        float S[8];
        EDGE_SUM(S, s, e);
        h8 sv = Y8[(size_t)node * 8 + q];
        ACC8(S, sv);
        float dv = dinv[node];
        h8 o;
        float t0 = fmaxf(dv * S[0] + bq[0], 0.f), t1 = fmaxf(dv * S[1] + bq[1], 0.f);
        float t2 = fmaxf(dv * S[2] + bq[2], 0.f), t3 = fmaxf(dv * S[3] + bq[3], 0.f);
        float t4 = fmaxf(dv * S[4] + bq[4], 0.f), t5 = fmaxf(dv * S[5] + bq[5], 0.f);
        float t6 = fmaxf(dv * S[6] + bq[6], 0.f), t7 = fmaxf(dv * S[7] + bq[7], 0.f);
        o.a = __floats2half2_rn(t0, t1);
        o.b = __floats2half2_rn(t2, t3);
        o.c = __floats2half2_rn(t4, t5);
        o.d = __floats2half2_rn(t6, t7);
        H8[(size_t)node * 8 + q] = o;
    }
}

// Layer-2 agg + fused global_mean_pool: h row is never stored; each group
// accumulates its 2 CONSECUTIVE nodes' relu(h) into registers and flushes to
// psums via native f32 global atomics on graph change (batch is sorted).
__global__ __launch_bounds__(256) void agg_pool_kernel(
        const h8* __restrict__ Y8, const unsigned* __restrict__ bedges,
        const int* __restrict__ offs, const float* __restrict__ dinv,
        const float* __restrict__ bias, const int* __restrict__ batch,
        float* __restrict__ psums, int* __restrict__ pcnt, int N) {
    __shared__ unsigned eb[CAP];
    __shared__ int off[65];
    int blk = blockIdx.x;
    int b = blk >> 1, half = blk & 1;
    int tid = threadIdx.x;
    if (tid < 65) off[tid] = offs[(size_t)b * (BNODES + 1) + half * 64 + tid];
    __syncthreads();
    int e0 = off[0];
    int ecnt = off[64] - e0;
    const unsigned* gp = bedges + (size_t)b * CAP + e0;
    for (int i = tid; i < ecnt; i += 256) eb[i] = gp[i];
    __syncthreads();
    int gg = tid >> 3, q = tid & 7;
    float bq[8];
#pragma unroll
    for (int j = 0; j < 8; j++) bq[j] = bias[q * 8 + j];
    float P[8];
#pragma unroll
    for (int j = 0; j < 8; j++) P[j] = 0.f;
    int curg = -1, pc = 0;
#pragma unroll
    for (int rr = 0; rr < 2; rr++) {
        int r = gg * 2 + rr;              // 2 consecutive nodes per group
        int node = (b << BSH) + half * 64 + r;
        if (node >= N) continue;
        int s = off[r] - e0, e = off[r + 1] - e0;
        float S[8];
        EDGE_SUM(S, s, e);
        h8 sv = Y8[(size_t)node * 8 + q];
        ACC8(S, sv);
        float dv = dinv[node];
#pragma unroll
        for (int j = 0; j < 8; j++) S[j] = fmaxf(dv * S[j] + bq[j], 0.f);
        int bg = batch[node];
        if (bg != curg) {
            if (curg >= 0) {
#pragma unroll
                for (int j = 0; j < 8; j++) atomicAdd(&psums[curg * DF + q * 8 + j], P[j]);
                if (q == 0) atomicAdd(&pcnt[curg], pc);
            }
#pragma unroll
            for (int j = 0; j < 8; j++) P[j] = S[j];
            curg = bg; pc = 1;
        } else {
#pragma unroll
            for (int j = 0; j < 8; j++) P[j] += S[j];
            pc++;
        }
    }
    if (curg >= 0) {
#pragma unroll
        for (int j = 0; j < 8; j++) atomicAdd(&psums[curg * DF + q * 8 + j], P[j]);
        if (q == 0) atomicAdd(&pcnt[curg], pc);
    }
}

// ---------------- head ----------------

__global__ void final_kernel(const float* __restrict__ sums, const int* __restrict__ cnts,
                             const float* __restrict__ Wp, const float* __restrict__ bp,
                             float* __restrict__ out) {
    int g = blockIdx.x, j = threadIdx.x;
    __shared__ float hg[64];
    float c = fmaxf((float)cnts[g], 1.f);
    hg[j] = sums[g * DF + j] / c;
    __syncthreads();
    float acc = bp[j];
#pragma unroll
    for (int k = 0; k < 64; k++) acc += hg[k] * Wp[k * DF + j];
    out[g * DF + j] = acc;
}

// ---------------- launch ----------------

extern "C" void kernel_launch(void* const* d_in, const int* in_sizes, int n_in,
                              void* d_out, int out_size, void* d_ws, size_t ws_size,
                              hipStream_t stream) {
    const float* x     = (const float*)d_in[0];
    const int*   ei    = (const int*)d_in[1];
    const int*   batch = (const int*)d_in[2];
    const float* W1    = (const float*)d_in[3];
    const float* b1    = (const float*)d_in[4];
    const float* W2    = (const float*)d_in[5];
    const float* b2    = (const float*)d_in[6];
    const float* Wp    = (const float*)d_in[7];
    const float* bp    = (const float*)d_in[8];

    int N = in_sizes[0] / DF;
    int E = in_sizes[1] / 2;
    const int* src = ei;
    const int* dst = ei + E;
    int NB = (N + BNODES - 1) >> BSH;
    int quadOK = ((E & 3) == 0) && (((uintptr_t)ei & 15) == 0) && (((uintptr_t)dst & 15) == 0);

    char* ws = (char*)d_ws;
    auto alloc = [&](size_t bytes) {
        void* p = (void*)ws;
        ws += (bytes + 255) / 256 * 256;
        return p;
    };
    // zero-region: bucketCur | psums | pcnt (single memset)
    size_t zPsums = ((size_t)NB * 4 + 255) / 256 * 256;
    size_t zPcnt  = zPsums + 64 * DF * 4;
    size_t zTotal = zPcnt + 256;
    char*     zbase     = (char*)alloc(zTotal);
    int*      bucketCur = (int*)zbase;
    float*    psums     = (float*)(zbase + zPsums);
    int*      pcnt      = (int*)(zbase + zPcnt);

    float*    dinv      = (float*)alloc((size_t)N * 4);
    unsigned* bedges    = (unsigned*)alloc((size_t)NB * CAP * 4);
    int*      offs      = (int*)alloc((size_t)NB * (BNODES + 1) * 4);
    h4*       y2        = (h4*)alloc((size_t)N * DF * 2);
    h4*       h2        = (h4*)alloc((size_t)N * DF * 2);

    hipMemsetAsync(zbase, 0, zTotal, stream);

    if (quadOK) {
        int nq = E >> 2;
        int pblocks = (nq + 2047) / 2048;
        part_kernel<<<pblocks, 512, 0, stream>>>(src, dst, (const int4*)src, (const int4*)dst,
                                                 E, bedges, bucketCur, NB);
    } else {
        part_scalar_kernel<<<1024, 256, 0, stream>>>(src, dst, E, bedges, bucketCur);
    }
    sort_kernel<<<NB, 256, 0, stream>>>(bedges, bucketCur, offs, dinv, N);

    gemm_f32in<<<(N + 15) / 16, 256, 0, stream>>>((const float4*)x, (const float4*)W1, dinv,
                                                  y2, N);
    agg_kernel<<<2 * NB, 256, 0, stream>>>((const h8*)y2, bedges, offs, dinv,
                                           b1, (h8*)h2, N);
    gemm_f16in<<<(N + 15) / 16, 256, 0, stream>>>(h2, (const float4*)W2, dinv,
                                                  y2, N);
    agg_pool_kernel<<<2 * NB, 256, 0, stream>>>((const h8*)y2, bedges, offs, dinv,
                                                b2, batch, psums, pcnt, N);

    final_kernel<<<64, 64, 0, stream>>>(psums, pcnt, Wp, bp, (float*)d_out);
}

// Round 10
// 248.784 us; speedup vs baseline: 2.7702x; 2.7702x over previous
//
#include <hip/hip_runtime.h>
#include <hip/hip_fp16.h>

// TemporalGCN: 2x GCNConv(64->64) + relu, global_mean_pool(64 graphs), linear 64->64.
// R10 = R7 structure (separate pool; global-atomic pool fusion in R9 caused 3.2M
// serialized f32 atomics = 522us) + R8's good parts (8-deep gather unroll,
// 512-thread part_kernel).
// Pipeline: part -> sort(+dinv) -> gemm1 -> agg1 -> gemm2 -> agg2 -> pool -> final.

#define DF 64
#define BSH 7                 // bucket = 128 consecutive dst nodes
#define BNODES 128
#define CAP 4096              // per-bucket edge capacity (mean 2048, >40 sigma)

struct alignas(8)  h4 { __half2 a, b; };        // 4 halves = 8B
struct alignas(16) h8 { __half2 a, b, c, d; };  // 8 halves = 16B

// ---------------- P1: partition edges into dst/128 buckets ----------------

__global__ __launch_bounds__(512) void part_kernel(
        const int* __restrict__ src, const int* __restrict__ dst,
        const int4* __restrict__ src4, const int4* __restrict__ dst4,
        int E, unsigned* __restrict__ bedges, int* __restrict__ bucketCur, int nb) {
    __shared__ int lcnt[1024];
    __shared__ int lbase[1024];
    int tid = threadIdx.x;
    for (int t = tid; t < nb; t += 512) lcnt[t] = 0;
    __syncthreads();
    int nq = E >> 2;
    unsigned packed[16];
    int bkt[16];
    int rk[16];
    int qbase = blockIdx.x * 2048;        // 2048 quads = 8192 edges / block
#pragma unroll
    for (int c = 0; c < 4; c++) {
        int qi = qbase + c * 512 + tid;
        int4 s = {0, 0, 0, 0}, d = {0, 0, 0, 0};
        bool v = qi < nq;
        if (v) { s = src4[qi]; d = dst4[qi]; }
        packed[4*c+0] = (unsigned)s.x | ((unsigned)(d.x & (BNODES-1)) << 24);
        packed[4*c+1] = (unsigned)s.y | ((unsigned)(d.y & (BNODES-1)) << 24);
        packed[4*c+2] = (unsigned)s.z | ((unsigned)(d.z & (BNODES-1)) << 24);
        packed[4*c+3] = (unsigned)s.w | ((unsigned)(d.w & (BNODES-1)) << 24);
        bkt[4*c+0] = v ? (d.x >> BSH) : -1;
        bkt[4*c+1] = v ? (d.y >> BSH) : -1;
        bkt[4*c+2] = v ? (d.z >> BSH) : -1;
        bkt[4*c+3] = v ? (d.w >> BSH) : -1;
    }
#pragma unroll
    for (int j = 0; j < 16; j++)
        rk[j] = (bkt[j] >= 0) ? atomicAdd(&lcnt[bkt[j]], 1) : 0;
    __syncthreads();
    for (int t = tid; t < nb; t += 512)
        lbase[t] = lcnt[t] ? atomicAdd(&bucketCur[t], lcnt[t]) : 0;
    __syncthreads();
#pragma unroll
    for (int j = 0; j < 16; j++) {
        if (bkt[j] >= 0) {
            int pos = lbase[bkt[j]] + rk[j];
            if (pos < CAP) bedges[(size_t)bkt[j] * CAP + pos] = packed[j];
        }
    }
    if (blockIdx.x == 0 && tid < (E & 3)) {
        int e = nq * 4 + tid;
        int sv = src[e], dv = dst[e];
        int b = dv >> BSH;
        int pos = atomicAdd(&bucketCur[b], 1);
        if (pos < CAP)
            bedges[(size_t)b * CAP + pos] =
                (unsigned)sv | ((unsigned)(dv & (BNODES-1)) << 24);
    }
}

__global__ void part_scalar_kernel(const int* __restrict__ src, const int* __restrict__ dst,
                                   int E, unsigned* __restrict__ bedges,
                                   int* __restrict__ bucketCur) {
    int stride = gridDim.x * blockDim.x;
    for (int e = blockIdx.x * blockDim.x + threadIdx.x; e < E; e += stride) {
        int sv = src[e], dv = dst[e];
        int b = dv >> BSH;
        int pos = atomicAdd(&bucketCur[b], 1);
        if (pos < CAP)
            bedges[(size_t)b * CAP + pos] =
                (unsigned)sv | ((unsigned)(dv & (BNODES-1)) << 24);
    }
}

// ------- P2: per-bucket LDS counting sort (int atomics only) + offsets + dinv -------

__global__ __launch_bounds__(256) void sort_kernel(
        unsigned* __restrict__ bedges, const int* __restrict__ bucketCur,
        int* __restrict__ offs, float* __restrict__ dinv, int N) {
    __shared__ unsigned ein[CAP];
    __shared__ unsigned eout[CAP];
    __shared__ int cnt[BNODES];
    __shared__ int sc[BNODES];
    __shared__ int off[BNODES + 1];
    __shared__ int cur[BNODES];
    int b = blockIdx.x, tid = threadIdx.x;
    int n = min(bucketCur[b], CAP);
    unsigned* gp = bedges + (size_t)b * CAP;
    if (tid < BNODES) cnt[tid] = 0;
    __syncthreads();
    for (int i = tid; i < n; i += 256) {
        unsigned u = gp[i];
        ein[i] = u;
        atomicAdd(&cnt[u >> 24], 1);      // native ds int atomic
    }
    __syncthreads();
    if (tid < BNODES) sc[tid] = cnt[tid];
    __syncthreads();
    for (int d = 1; d < BNODES; d <<= 1) {
        int v = (tid >= d && tid < BNODES) ? sc[tid - d] : 0;
        __syncthreads();
        if (tid < BNODES) sc[tid] += v;
        __syncthreads();
    }
    if (tid < BNODES) {
        off[tid + 1] = sc[tid];
        cur[tid] = sc[tid] - cnt[tid];
        if (tid == 0) off[0] = 0;
    }
    __syncthreads();
    for (int i = tid; i < n; i += 256) {
        unsigned u = ein[i];
        int p = atomicAdd(&cur[u >> 24], 1);
        eout[p] = u;
    }
    __syncthreads();
    for (int i = tid; i < n; i += 256) gp[i] = eout[i];
    if (tid <= BNODES) offs[(size_t)b * (BNODES + 1) + tid] = off[tid];
    int node = (b << BSH) + tid;
    if (tid < BNODES && node < N)
        dinv[node] = 1.0f / sqrtf((float)(cnt[tid] + 1));   // deg = in + self-loop
}

// ---------------- per-layer compute ----------------

// Y[row][c] = (sum_k X[row][k] * W[k][c]) * dinv[row]; f32 input -> fp16 out.
__global__ void gemm_f32in(const float4* __restrict__ X4, const float4* __restrict__ W4,
                           const float* __restrict__ dinv, h4* __restrict__ Y2, int n) {
    __shared__ float4 Wl4[64][16];   // [k][c4]
    __shared__ float Xl[16][68];     // padded: conflict-free broadcast
    int tid = threadIdx.x;
    float4* Wf = &Wl4[0][0];
#pragma unroll
    for (int i = 0; i < 4; i++) {
        int idx = tid + i * 256;     // idx = k*16 + c4
        Wf[idx] = W4[idx];
    }
    int row0 = blockIdx.x * 16;
    int r = tid >> 4, c4 = tid & 15;
    {
        int row = row0 + r;
        float4 v = (row < n) ? X4[(size_t)row * 16 + c4] : float4{0.f, 0.f, 0.f, 0.f};
        Xl[r][c4 * 4 + 0] = v.x;
        Xl[r][c4 * 4 + 1] = v.y;
        Xl[r][c4 * 4 + 2] = v.z;
        Xl[r][c4 * 4 + 3] = v.w;
    }
    __syncthreads();
    float ax = 0.f, ay = 0.f, az = 0.f, aw = 0.f;
#pragma unroll
    for (int k = 0; k < 64; k++) {
        float xv = Xl[r][k];
        float4 w = Wl4[k][c4];
        ax += xv * w.x;
        ay += xv * w.y;
        az += xv * w.z;
        aw += xv * w.w;
    }
    int row = row0 + r;
    if (row < n) {
        float dv = dinv[row];
        h4 o;
        o.a = __floats2half2_rn(ax * dv, ay * dv);
        o.b = __floats2half2_rn(az * dv, aw * dv);
        Y2[(size_t)row * 16 + c4] = o;
    }
}

// same, fp16 input (layer 2: X = h stored as fp16)
__global__ void gemm_f16in(const h4* __restrict__ X2, const float4* __restrict__ W4,
                           const float* __restrict__ dinv, h4* __restrict__ Y2, int n) {
    __shared__ float4 Wl4[64][16];
    __shared__ float Xl[16][68];
    int tid = threadIdx.x;
    float4* Wf = &Wl4[0][0];
#pragma unroll
    for (int i = 0; i < 4; i++) {
        int idx = tid + i * 256;
        Wf[idx] = W4[idx];
    }
    int row0 = blockIdx.x * 16;
    int r = tid >> 4, c4 = tid & 15;
    {
        int row = row0 + r;
        h4 hv = (row < n) ? X2[(size_t)row * 16 + c4] : h4{__half2{0, 0}, __half2{0, 0}};
        float2 va = __half22float2(hv.a), vb = __half22float2(hv.b);
        Xl[r][c4 * 4 + 0] = va.x;
        Xl[r][c4 * 4 + 1] = va.y;
        Xl[r][c4 * 4 + 2] = vb.x;
        Xl[r][c4 * 4 + 3] = vb.y;
    }
    __syncthreads();
    float ax = 0.f, ay = 0.f, az = 0.f, aw = 0.f;
#pragma unroll
    for (int k = 0; k < 64; k++) {
        float xv = Xl[r][k];
        float4 w = Wl4[k][c4];
        ax += xv * w.x;
        ay += xv * w.y;
        az += xv * w.z;
        aw += xv * w.w;
    }
    int row = row0 + r;
    if (row < n) {
        float dv = dinv[row];
        h4 o;
        o.a = __floats2half2_rn(ax * dv, ay * dv);
        o.b = __floats2half2_rn(az * dv, aw * dv);
        Y2[(size_t)row * 16 + c4] = o;
    }
}

#define ACC8(A, w)                                        \
    { float2 _p = __half22float2((w).a);                  \
      A[0] += _p.x; A[1] += _p.y;                         \
      _p = __half22float2((w).b);                         \
      A[2] += _p.x; A[3] += _p.y;                         \
      _p = __half22float2((w).c);                         \
      A[4] += _p.x; A[5] += _p.y;                         \
      _p = __half22float2((w).d);                         \
      A[6] += _p.x; A[7] += _p.y; }

// Edge-sum core: S[8] = sum over node's in-edges of y[src][q-slice]; 8 loads in flight.
#define EDGE_SUM(S_, s_, e_)                                                   \
    float A0[8], A1[8], A2[8], A3[8];                                          \
    _Pragma("unroll")                                                          \
    for (int j = 0; j < 8; j++) { A0[j] = 0.f; A1[j] = 0.f; A2[j] = 0.f; A3[j] = 0.f; } \
    {                                                                          \
        int i = (s_);                                                          \
        for (; i + 7 < (e_); i += 8) {                                         \
            unsigned u0 = eb[i],     u1 = eb[i + 1], u2 = eb[i + 2], u3 = eb[i + 3]; \
            unsigned u4 = eb[i + 4], u5 = eb[i + 5], u6 = eb[i + 6], u7 = eb[i + 7]; \
            h8 w0 = Y8[(size_t)(u0 & 0xFFFFFFu) * 8 + q];                      \
            h8 w1 = Y8[(size_t)(u1 & 0xFFFFFFu) * 8 + q];                      \
            h8 w2 = Y8[(size_t)(u2 & 0xFFFFFFu) * 8 + q];                      \
            h8 w3 = Y8[(size_t)(u3 & 0xFFFFFFu) * 8 + q];                      \
            h8 w4 = Y8[(size_t)(u4 & 0xFFFFFFu) * 8 + q];                      \
            h8 w5 = Y8[(size_t)(u5 & 0xFFFFFFu) * 8 + q];                      \
            h8 w6 = Y8[(size_t)(u6 & 0xFFFFFFu) * 8 + q];                      \
            h8 w7 = Y8[(size_t)(u7 & 0xFFFFFFu) * 8 + q];                      \
            ACC8(A0, w0); ACC8(A1, w1); ACC8(A2, w2); ACC8(A3, w3);            \
            ACC8(A0, w4); ACC8(A1, w5); ACC8(A2, w6); ACC8(A3, w7);            \
        }                                                                      \
        for (; i + 3 < (e_); i += 4) {                                         \
            unsigned u0 = eb[i], u1 = eb[i + 1], u2 = eb[i + 2], u3 = eb[i + 3]; \
            h8 w0 = Y8[(size_t)(u0 & 0xFFFFFFu) * 8 + q];                      \
            h8 w1 = Y8[(size_t)(u1 & 0xFFFFFFu) * 8 + q];                      \
            h8 w2 = Y8[(size_t)(u2 & 0xFFFFFFu) * 8 + q];                      \
            h8 w3 = Y8[(size_t)(u3 & 0xFFFFFFu) * 8 + q];                      \
            ACC8(A0, w0); ACC8(A1, w1); ACC8(A2, w2); ACC8(A3, w3);            \
        }                                                                      \
        for (; i < (e_); i++) {                                                \
            unsigned u = eb[i];                                                \
            h8 w = Y8[(size_t)(u & 0xFFFFFFu) * 8 + q];                        \
            ACC8(A0, w);                                                       \
        }                                                                      \
    }                                                                          \
    _Pragma("unroll")                                                          \
    for (int j = 0; j < 8; j++) S_[j] = A0[j] + A1[j] + A2[j] + A3[j];

// H[node][:] = relu(dinv*(sum + y[node]) + b) -> fp16 store.
// One block per HALF bucket (64 nodes); 256 thr = 32 groups x 8 lanes, h8/lane.
__global__ __launch_bounds__(256) void agg_kernel(
        const h8* __restrict__ Y8, const unsigned* __restrict__ bedges,
        const int* __restrict__ offs, const float* __restrict__ dinv,
        const float* __restrict__ bias, h8* __restrict__ H8, int N) {
    __shared__ unsigned eb[CAP];
    __shared__ int off[65];
    int blk = blockIdx.x;
    int b = blk >> 1, half = blk & 1;
    int tid = threadIdx.x;
    if (tid < 65) off[tid] = offs[(size_t)b * (BNODES + 1) + half * 64 + tid];
    __syncthreads();
    int e0 = off[0];
    int ecnt = off[64] - e0;
    const unsigned* gp = bedges + (size_t)b * CAP + e0;
    for (int i = tid; i < ecnt; i += 256) eb[i] = gp[i];
    __syncthreads();
    int gg = tid >> 3, q = tid & 7;
    float bq[8];
#pragma unroll
    for (int j = 0; j < 8; j++) bq[j] = bias[q * 8 + j];
#pragma unroll
    for (int rr = 0; rr < 2; rr++) {
        int r = gg + rr * 32;
        int node = (b << BSH) + half * 64 + r;
        if (node >= N) continue;
        int s = off[r] - e0, e = off[r + 1] - e0;
        float S[8];
        EDGE_SUM(S, s, e);
        h8 sv = Y8[(size_t)node * 8 + q];
        ACC8(S, sv);
        float dv = dinv[node];
        float t0 = fmaxf(dv * S[0] + bq[0], 0.f), t1 = fmaxf(dv * S[1] + bq[1], 0.f);
        float t2 = fmaxf(dv * S[2] + bq[2], 0.f), t3 = fmaxf(dv * S[3] + bq[3], 0.f);
        float t4 = fmaxf(dv * S[4] + bq[4], 0.f), t5 = fmaxf(dv * S[5] + bq[5], 0.f);
        float t6 = fmaxf(dv * S[6] + bq[6], 0.f), t7 = fmaxf(dv * S[7] + bq[7], 0.f);
        h8 o;
        o.a = __floats2half2_rn(t0, t1);
        o.b = __floats2half2_rn(t2, t3);
        o.c = __floats2half2_rn(t4, t5);
        o.d = __floats2half2_rn(t6, t7);
        H8[(size_t)node * 8 + q] = o;
    }
}

// ---------------- pooling + head ----------------

// Each wave owns a 256-row run; 4 lane-groups of 16 take rows step 4; fp16 input.
// ~200K global f32 atomics total (run-length flush granularity = 256 rows).
__global__ void pool_kernel(const h4* __restrict__ H2, const int* __restrict__ batch,
                            float* __restrict__ sums, int* __restrict__ cnts, int n) {
    int gw = (blockIdx.x * blockDim.x + threadIdx.x) >> 6;
    int lane = threadIdx.x & 63;
    int g = lane >> 4, q = lane & 15;
    int start = gw * 256;
    if (start >= n) return;
    int end = min(start + 256, n);
    float ax = 0.f, ay = 0.f, az = 0.f, aw = 0.f;
    int cur = -1, run = 0;
    for (int i = start + g; i < end; i += 4) {
        int b = batch[i];
        if (b != cur) {
            if (run > 0) {
                atomicAdd(&sums[cur * DF + q * 4 + 0], ax);
                atomicAdd(&sums[cur * DF + q * 4 + 1], ay);
                atomicAdd(&sums[cur * DF + q * 4 + 2], az);
                atomicAdd(&sums[cur * DF + q * 4 + 3], aw);
                if (q == 0) atomicAdd(&cnts[cur], run);
            }
            cur = b; run = 0;
            ax = ay = az = aw = 0.f;
        }
        h4 hv = H2[(size_t)i * 16 + q];
        float2 va = __half22float2(hv.a), vb = __half22float2(hv.b);
        ax += va.x; ay += va.y; az += vb.x; aw += vb.y;
        run++;
    }
    if (run > 0) {
        atomicAdd(&sums[cur * DF + q * 4 + 0], ax);
        atomicAdd(&sums[cur * DF + q * 4 + 1], ay);
        atomicAdd(&sums[cur * DF + q * 4 + 2], az);
        atomicAdd(&sums[cur * DF + q * 4 + 3], aw);
        if (q == 0) atomicAdd(&cnts[cur], run);
    }
}

__global__ void final_kernel(const float* __restrict__ sums, const int* __restrict__ cnts,
                             const float* __restrict__ Wp, const float* __restrict__ bp,
                             float* __restrict__ out) {
    int g = blockIdx.x, j = threadIdx.x;
    __shared__ float hg[64];
    float c = fmaxf((float)cnts[g], 1.f);
    hg[j] = sums[g * DF + j] / c;
    __syncthreads();
    float acc = bp[j];
#pragma unroll
    for (int k = 0; k < 64; k++) acc += hg[k] * Wp[k * DF + j];
    out[g * DF + j] = acc;
}

// ---------------- launch ----------------

extern "C" void kernel_launch(void* const* d_in, const int* in_sizes, int n_in,
                              void* d_out, int out_size, void* d_ws, size_t ws_size,
                              hipStream_t stream) {
    const float* x     = (const float*)d_in[0];
    const int*   ei    = (const int*)d_in[1];
    const int*   batch = (const int*)d_in[2];
    const float* W1    = (const float*)d_in[3];
    const float* b1    = (const float*)d_in[4];
    const float* W2    = (const float*)d_in[5];
    const float* b2    = (const float*)d_in[6];
    const float* Wp    = (const float*)d_in[7];
    const float* bp    = (const float*)d_in[8];

    int N = in_sizes[0] / DF;
    int E = in_sizes[1] / 2;
    const int* src = ei;
    const int* dst = ei + E;
    int NB = (N + BNODES - 1) >> BSH;
    int quadOK = ((E & 3) == 0) && (((uintptr_t)ei & 15) == 0) && (((uintptr_t)dst & 15) == 0);

    char* ws = (char*)d_ws;
    auto alloc = [&](size_t bytes) {
        void* p = (void*)ws;
        ws += (bytes + 255) / 256 * 256;
        return p;
    };
    // zero-region: bucketCur | psums | pcnt (single memset)
    size_t zPsums = ((size_t)NB * 4 + 255) / 256 * 256;
    size_t zPcnt  = zPsums + 64 * DF * 4;
    size_t zTotal = zPcnt + 256;
    char*     zbase     = (char*)alloc(zTotal);
    int*      bucketCur = (int*)zbase;
    float*    psums     = (float*)(zbase + zPsums);
    int*      pcnt      = (int*)(zbase + zPcnt);

    float*    dinv      = (float*)alloc((size_t)N * 4);
    unsigned* bedges    = (unsigned*)alloc((size_t)NB * CAP * 4);
    int*      offs      = (int*)alloc((size_t)NB * (BNODES + 1) * 4);
    h4*       y2        = (h4*)alloc((size_t)N * DF * 2);
    h4*       h2        = (h4*)alloc((size_t)N * DF * 2);

    hipMemsetAsync(zbase, 0, zTotal, stream);

    if (quadOK) {
        int nq = E >> 2;
        int pblocks = (nq + 2047) / 2048;
        part_kernel<<<pblocks, 512, 0, stream>>>(src, dst, (const int4*)src, (const int4*)dst,
                                                 E, bedges, bucketCur, NB);
    } else {
        part_scalar_kernel<<<1024, 256, 0, stream>>>(src, dst, E, bedges, bucketCur);
    }
    sort_kernel<<<NB, 256, 0, stream>>>(bedges, bucketCur, offs, dinv, N);

    gemm_f32in<<<(N + 15) / 16, 256, 0, stream>>>((const float4*)x, (const float4*)W1, dinv,
                                                  y2, N);
    agg_kernel<<<2 * NB, 256, 0, stream>>>((const h8*)y2, bedges, offs, dinv,
                                           b1, (h8*)h2, N);
    gemm_f16in<<<(N + 15) / 16, 256, 0, stream>>>(h2, (const float4*)W2, dinv,
                                                  y2, N);
    agg_kernel<<<2 * NB, 256, 0, stream>>>((const h8*)y2, bedges, offs, dinv,
                                           b2, (h8*)h2, N);

    int waves = (N + 255) / 256;
    pool_kernel<<<(waves + 3) / 4, 256, 0, stream>>>(h2, batch, psums, pcnt, N);
    final_kernel<<<64, 64, 0, stream>>>(psums, pcnt, Wp, bp, (float*)d_out);
}

// Round 11
// 247.853 us; speedup vs baseline: 2.7806x; 1.0038x over previous
//
#include <hip/hip_runtime.h>
#include <hip/hip_fp16.h>

// TemporalGCN: 2x GCNConv(64->64) + relu, global_mean_pool(64 graphs), linear 64->64.
// R11: quarter-bucket agg (32 nodes/block, 1 node per 8-lane group, grid 6256,
// 4.3KB LDS) for load balance + latency hiding; pool uses native f32 global
// atomics (unsafeAtomicAdd, not CAS); sort at 512 threads.
// Pipeline: part -> sort(+dinv) -> gemm1 -> agg1 -> gemm2 -> agg2 -> pool -> final.

#define DF 64
#define BSH 7                 // bucket = 128 consecutive dst nodes
#define BNODES 128
#define CAP 4096              // per-bucket edge capacity (mean 2048, >40 sigma)
#define QCAP 1024             // staged edges per quarter (mean 512, ~22 sigma)

struct alignas(8)  h4 { __half2 a, b; };        // 4 halves = 8B
struct alignas(16) h8 { __half2 a, b, c, d; };  // 8 halves = 16B

// ---------------- P1: partition edges into dst/128 buckets ----------------

__global__ __launch_bounds__(512) void part_kernel(
        const int* __restrict__ src, const int* __restrict__ dst,
        const int4* __restrict__ src4, const int4* __restrict__ dst4,
        int E, unsigned* __restrict__ bedges, int* __restrict__ bucketCur, int nb) {
    __shared__ int lcnt[1024];
    __shared__ int lbase[1024];
    int tid = threadIdx.x;
    for (int t = tid; t < nb; t += 512) lcnt[t] = 0;
    __syncthreads();
    int nq = E >> 2;
    unsigned packed[16];
    int bkt[16];
    int rk[16];
    int qbase = blockIdx.x * 2048;        // 2048 quads = 8192 edges / block
#pragma unroll
    for (int c = 0; c < 4; c++) {
        int qi = qbase + c * 512 + tid;
        int4 s = {0, 0, 0, 0}, d = {0, 0, 0, 0};
        bool v = qi < nq;
        if (v) { s = src4[qi]; d = dst4[qi]; }
        packed[4*c+0] = (unsigned)s.x | ((unsigned)(d.x & (BNODES-1)) << 24);
        packed[4*c+1] = (unsigned)s.y | ((unsigned)(d.y & (BNODES-1)) << 24);
        packed[4*c+2] = (unsigned)s.z | ((unsigned)(d.z & (BNODES-1)) << 24);
        packed[4*c+3] = (unsigned)s.w | ((unsigned)(d.w & (BNODES-1)) << 24);
        bkt[4*c+0] = v ? (d.x >> BSH) : -1;
        bkt[4*c+1] = v ? (d.y >> BSH) : -1;
        bkt[4*c+2] = v ? (d.z >> BSH) : -1;
        bkt[4*c+3] = v ? (d.w >> BSH) : -1;
    }
#pragma unroll
    for (int j = 0; j < 16; j++)
        rk[j] = (bkt[j] >= 0) ? atomicAdd(&lcnt[bkt[j]], 1) : 0;
    __syncthreads();
    for (int t = tid; t < nb; t += 512)
        lbase[t] = lcnt[t] ? atomicAdd(&bucketCur[t], lcnt[t]) : 0;
    __syncthreads();
#pragma unroll
    for (int j = 0; j < 16; j++) {
        if (bkt[j] >= 0) {
            int pos = lbase[bkt[j]] + rk[j];
            if (pos < CAP) bedges[(size_t)bkt[j] * CAP + pos] = packed[j];
        }
    }
    if (blockIdx.x == 0 && tid < (E & 3)) {
        int e = nq * 4 + tid;
        int sv = src[e], dv = dst[e];
        int b = dv >> BSH;
        int pos = atomicAdd(&bucketCur[b], 1);
        if (pos < CAP)
            bedges[(size_t)b * CAP + pos] =
                (unsigned)sv | ((unsigned)(dv & (BNODES-1)) << 24);
    }
}

__global__ void part_scalar_kernel(const int* __restrict__ src, const int* __restrict__ dst,
                                   int E, unsigned* __restrict__ bedges,
                                   int* __restrict__ bucketCur) {
    int stride = gridDim.x * blockDim.x;
    for (int e = blockIdx.x * blockDim.x + threadIdx.x; e < E; e += stride) {
        int sv = src[e], dv = dst[e];
        int b = dv >> BSH;
        int pos = atomicAdd(&bucketCur[b], 1);
        if (pos < CAP)
            bedges[(size_t)b * CAP + pos] =
                (unsigned)sv | ((unsigned)(dv & (BNODES-1)) << 24);
    }
}

// ------- P2: per-bucket LDS counting sort (int atomics only) + offsets + dinv -------

__global__ __launch_bounds__(512) void sort_kernel(
        unsigned* __restrict__ bedges, const int* __restrict__ bucketCur,
        int* __restrict__ offs, float* __restrict__ dinv, int N) {
    __shared__ unsigned ein[CAP];
    __shared__ unsigned eout[CAP];
    __shared__ int cnt[BNODES];
    __shared__ int sc[BNODES];
    __shared__ int off[BNODES + 1];
    __shared__ int cur[BNODES];
    int b = blockIdx.x, tid = threadIdx.x;
    int n = min(bucketCur[b], CAP);
    unsigned* gp = bedges + (size_t)b * CAP;
    if (tid < BNODES) cnt[tid] = 0;
    __syncthreads();
    for (int i = tid; i < n; i += 512) {
        unsigned u = gp[i];
        ein[i] = u;
        atomicAdd(&cnt[u >> 24], 1);      // native ds int atomic
    }
    __syncthreads();
    if (tid < BNODES) sc[tid] = cnt[tid];
    __syncthreads();
    for (int d = 1; d < BNODES; d <<= 1) {
        int v = (tid >= d && tid < BNODES) ? sc[tid - d] : 0;
        __syncthreads();
        if (tid < BNODES) sc[tid] += v;
        __syncthreads();
    }
    if (tid < BNODES) {
        off[tid + 1] = sc[tid];
        cur[tid] = sc[tid] - cnt[tid];
        if (tid == 0) off[0] = 0;
    }
    __syncthreads();
    for (int i = tid; i < n; i += 512) {
        unsigned u = ein[i];
        int p = atomicAdd(&cur[u >> 24], 1);
        eout[p] = u;
    }
    __syncthreads();
    for (int i = tid; i < n; i += 512) gp[i] = eout[i];
    if (tid <= BNODES) offs[(size_t)b * (BNODES + 1) + tid] = off[tid];
    int node = (b << BSH) + tid;
    if (tid < BNODES && node < N)
        dinv[node] = 1.0f / sqrtf((float)(cnt[tid] + 1));   // deg = in + self-loop
}

// ---------------- per-layer compute ----------------

// Y[row][c] = (sum_k X[row][k] * W[k][c]) * dinv[row]; f32 input -> fp16 out.
__global__ void gemm_f32in(const float4* __restrict__ X4, const float4* __restrict__ W4,
                           const float* __restrict__ dinv, h4* __restrict__ Y2, int n) {
    __shared__ float4 Wl4[64][16];   // [k][c4]
    __shared__ float Xl[16][68];     // padded: conflict-free broadcast
    int tid = threadIdx.x;
    float4* Wf = &Wl4[0][0];
#pragma unroll
    for (int i = 0; i < 4; i++) {
        int idx = tid + i * 256;     // idx = k*16 + c4
        Wf[idx] = W4[idx];
    }
    int row0 = blockIdx.x * 16;
    int r = tid >> 4, c4 = tid & 15;
    {
        int row = row0 + r;
        float4 v = (row < n) ? X4[(size_t)row * 16 + c4] : float4{0.f, 0.f, 0.f, 0.f};
        Xl[r][c4 * 4 + 0] = v.x;
        Xl[r][c4 * 4 + 1] = v.y;
        Xl[r][c4 * 4 + 2] = v.z;
        Xl[r][c4 * 4 + 3] = v.w;
    }
    __syncthreads();
    float ax = 0.f, ay = 0.f, az = 0.f, aw = 0.f;
#pragma unroll
    for (int k = 0; k < 64; k++) {
        float xv = Xl[r][k];
        float4 w = Wl4[k][c4];
        ax += xv * w.x;
        ay += xv * w.y;
        az += xv * w.z;
        aw += xv * w.w;
    }
    int row = row0 + r;
    if (row < n) {
        float dv = dinv[row];
        h4 o;
        o.a = __floats2half2_rn(ax * dv, ay * dv);
        o.b = __floats2half2_rn(az * dv, aw * dv);
        Y2[(size_t)row * 16 + c4] = o;
    }
}

// same, fp16 input (layer 2: X = h stored as fp16)
__global__ void gemm_f16in(const h4* __restrict__ X2, const float4* __restrict__ W4,
                           const float* __restrict__ dinv, h4* __restrict__ Y2, int n) {
    __shared__ float4 Wl4[64][16];
    __shared__ float Xl[16][68];
    int tid = threadIdx.x;
    float4* Wf = &Wl4[0][0];
#pragma unroll
    for (int i = 0; i < 4; i++) {
        int idx = tid + i * 256;
        Wf[idx] = W4[idx];
    }
    int row0 = blockIdx.x * 16;
    int r = tid >> 4, c4 = tid & 15;
    {
        int row = row0 + r;
        h4 hv = (row < n) ? X2[(size_t)row * 16 + c4] : h4{__half2{0, 0}, __half2{0, 0}};
        float2 va = __half22float2(hv.a), vb = __half22float2(hv.b);
        Xl[r][c4 * 4 + 0] = va.x;
        Xl[r][c4 * 4 + 1] = va.y;
        Xl[r][c4 * 4 + 2] = vb.x;
        Xl[r][c4 * 4 + 3] = vb.y;
    }
    __syncthreads();
    float ax = 0.f, ay = 0.f, az = 0.f, aw = 0.f;
#pragma unroll
    for (int k = 0; k < 64; k++) {
        float xv = Xl[r][k];
        float4 w = Wl4[k][c4];
        ax += xv * w.x;
        ay += xv * w.y;
        az += xv * w.z;
        aw += xv * w.w;
    }
    int row = row0 + r;
    if (row < n) {
        float dv = dinv[row];
        h4 o;
        o.a = __floats2half2_rn(ax * dv, ay * dv);
        o.b = __floats2half2_rn(az * dv, aw * dv);
        Y2[(size_t)row * 16 + c4] = o;
    }
}

#define ACC8(A, w)                                        \
    { float2 _p = __half22float2((w).a);                  \
      A[0] += _p.x; A[1] += _p.y;                         \
      _p = __half22float2((w).b);                         \
      A[2] += _p.x; A[3] += _p.y;                         \
      _p = __half22float2((w).c);                         \
      A[4] += _p.x; A[5] += _p.y;                         \
      _p = __half22float2((w).d);                         \
      A[6] += _p.x; A[7] += _p.y; }

// H[node][:] = relu(dinv*(sum + y[node]) + b) -> fp16 store.
// One block per QUARTER bucket (32 nodes); 256 thr = 32 groups x 8 lanes;
// ONE node per group (shortest serial chain), 8 gathers in flight.
__global__ __launch_bounds__(256) void agg_kernel(
        const h8* __restrict__ Y8, const unsigned* __restrict__ bedges,
        const int* __restrict__ offs, const float* __restrict__ dinv,
        const float* __restrict__ bias, h8* __restrict__ H8, int N) {
    __shared__ unsigned eb[QCAP];
    __shared__ int off[33];
    int blk = blockIdx.x;
    int b = blk >> 2, quad = blk & 3;
    int tid = threadIdx.x;
    if (tid < 33) off[tid] = offs[(size_t)b * (BNODES + 1) + quad * 32 + tid];
    __syncthreads();
    int e0 = off[0];
    int ecnt = off[32] - e0;
    const unsigned* gp = bedges + (size_t)b * CAP + e0;
    int staged = min(ecnt, QCAP);
    for (int i = tid; i < staged; i += 256) eb[i] = gp[i];
    __syncthreads();
    int gg = tid >> 3, q = tid & 7;
    int node = (b << BSH) + quad * 32 + gg;
    if (node >= N) return;
    int s = off[gg] - e0, e = off[gg + 1] - e0;
    int e1 = min(e, staged);                       // LDS-staged range end
    float bq[8];
#pragma unroll
    for (int j = 0; j < 8; j++) bq[j] = bias[q * 8 + j];
    float A0[8], A1[8], A2[8], A3[8];
#pragma unroll
    for (int j = 0; j < 8; j++) { A0[j] = 0.f; A1[j] = 0.f; A2[j] = 0.f; A3[j] = 0.f; }
    int i = s;
    for (; i + 7 < e1; i += 8) {
        unsigned u0 = eb[i],     u1 = eb[i + 1], u2 = eb[i + 2], u3 = eb[i + 3];
        unsigned u4 = eb[i + 4], u5 = eb[i + 5], u6 = eb[i + 6], u7 = eb[i + 7];
        h8 w0 = Y8[(size_t)(u0 & 0xFFFFFFu) * 8 + q];
        h8 w1 = Y8[(size_t)(u1 & 0xFFFFFFu) * 8 + q];
        h8 w2 = Y8[(size_t)(u2 & 0xFFFFFFu) * 8 + q];
        h8 w3 = Y8[(size_t)(u3 & 0xFFFFFFu) * 8 + q];
        h8 w4 = Y8[(size_t)(u4 & 0xFFFFFFu) * 8 + q];
        h8 w5 = Y8[(size_t)(u5 & 0xFFFFFFu) * 8 + q];
        h8 w6 = Y8[(size_t)(u6 & 0xFFFFFFu) * 8 + q];
        h8 w7 = Y8[(size_t)(u7 & 0xFFFFFFu) * 8 + q];
        ACC8(A0, w0); ACC8(A1, w1); ACC8(A2, w2); ACC8(A3, w3);
        ACC8(A0, w4); ACC8(A1, w5); ACC8(A2, w6); ACC8(A3, w7);
    }
    for (; i + 3 < e1; i += 4) {
        unsigned u0 = eb[i], u1 = eb[i + 1], u2 = eb[i + 2], u3 = eb[i + 3];
        h8 w0 = Y8[(size_t)(u0 & 0xFFFFFFu) * 8 + q];
        h8 w1 = Y8[(size_t)(u1 & 0xFFFFFFu) * 8 + q];
        h8 w2 = Y8[(size_t)(u2 & 0xFFFFFFu) * 8 + q];
        h8 w3 = Y8[(size_t)(u3 & 0xFFFFFFu) * 8 + q];
        ACC8(A0, w0); ACC8(A1, w1); ACC8(A2, w2); ACC8(A3, w3);
    }
    for (; i < e1; i++) {
        unsigned u = eb[i];
        h8 w = Y8[(size_t)(u & 0xFFFFFFu) * 8 + q];
        ACC8(A0, w);
    }
    for (i = (s > staged ? s : staged); i < e; i++) {   // rare overflow tail (global)
        unsigned u = gp[i];
        h8 w = Y8[(size_t)(u & 0xFFFFFFu) * 8 + q];
        ACC8(A0, w);
    }
    // self-loop + finalize
    h8 sv = Y8[(size_t)node * 8 + q];
    ACC8(A0, sv);
    float dv = dinv[node];
    float t0 = fmaxf(dv * (A0[0] + A1[0] + A2[0] + A3[0]) + bq[0], 0.f);
    float t1 = fmaxf(dv * (A0[1] + A1[1] + A2[1] + A3[1]) + bq[1], 0.f);
    float t2 = fmaxf(dv * (A0[2] + A1[2] + A2[2] + A3[2]) + bq[2], 0.f);
    float t3 = fmaxf(dv * (A0[3] + A1[3] + A2[3] + A3[3]) + bq[3], 0.f);
    float t4 = fmaxf(dv * (A0[4] + A1[4] + A2[4] + A3[4]) + bq[4], 0.f);
    float t5 = fmaxf(dv * (A0[5] + A1[5] + A2[5] + A3[5]) + bq[5], 0.f);
    float t6 = fmaxf(dv * (A0[6] + A1[6] + A2[6] + A3[6]) + bq[6], 0.f);
    float t7 = fmaxf(dv * (A0[7] + A1[7] + A2[7] + A3[7]) + bq[7], 0.f);
    h8 o;
    o.a = __floats2half2_rn(t0, t1);
    o.b = __floats2half2_rn(t2, t3);
    o.c = __floats2half2_rn(t4, t5);
    o.d = __floats2half2_rn(t6, t7);
    H8[(size_t)node * 8 + q] = o;
}

// ---------------- pooling + head ----------------

// Each wave owns a 256-row run; 4 lane-groups of 16 take rows step 4; fp16 input.
// Native f32 global atomics (unsafeAtomicAdd -> global_atomic_add_f32, no CAS).
__global__ void pool_kernel(const h4* __restrict__ H2, const int* __restrict__ batch,
                            float* __restrict__ sums, int* __restrict__ cnts, int n) {
    int gw = (blockIdx.x * blockDim.x + threadIdx.x) >> 6;
    int lane = threadIdx.x & 63;
    int g = lane >> 4, q = lane & 15;
    int start = gw * 256;
    if (start >= n) return;
    int end = min(start + 256, n);
    float ax = 0.f, ay = 0.f, az = 0.f, aw = 0.f;
    int cur = -1, run = 0;
    for (int i = start + g; i < end; i += 4) {
        int b = batch[i];
        if (b != cur) {
            if (run > 0) {
                unsafeAtomicAdd(&sums[cur * DF + q * 4 + 0], ax);
                unsafeAtomicAdd(&sums[cur * DF + q * 4 + 1], ay);
                unsafeAtomicAdd(&sums[cur * DF + q * 4 + 2], az);
                unsafeAtomicAdd(&sums[cur * DF + q * 4 + 3], aw);
                if (q == 0) atomicAdd(&cnts[cur], run);
            }
            cur = b; run = 0;
            ax = ay = az = aw = 0.f;
        }
        h4 hv = H2[(size_t)i * 16 + q];
        float2 va = __half22float2(hv.a), vb = __half22float2(hv.b);
        ax += va.x; ay += va.y; az += vb.x; aw += vb.y;
        run++;
    }
    if (run > 0) {
        unsafeAtomicAdd(&sums[cur * DF + q * 4 + 0], ax);
        unsafeAtomicAdd(&sums[cur * DF + q * 4 + 1], ay);
        unsafeAtomicAdd(&sums[cur * DF + q * 4 + 2], az);
        unsafeAtomicAdd(&sums[cur * DF + q * 4 + 3], aw);
        if (q == 0) atomicAdd(&cnts[cur], run);
    }
}

__global__ void final_kernel(const float* __restrict__ sums, const int* __restrict__ cnts,
                             const float* __restrict__ Wp, const float* __restrict__ bp,
                             float* __restrict__ out) {
    int g = blockIdx.x, j = threadIdx.x;
    __shared__ float hg[64];
    float c = fmaxf((float)cnts[g], 1.f);
    hg[j] = sums[g * DF + j] / c;
    __syncthreads();
    float acc = bp[j];
#pragma unroll
    for (int k = 0; k < 64; k++) acc += hg[k] * Wp[k * DF + j];
    out[g * DF + j] = acc;
}

// ---------------- launch ----------------

extern "C" void kernel_launch(void* const* d_in, const int* in_sizes, int n_in,
                              void* d_out, int out_size, void* d_ws, size_t ws_size,
                              hipStream_t stream) {
    const float* x     = (const float*)d_in[0];
    const int*   ei    = (const int*)d_in[1];
    const int*   batch = (const int*)d_in[2];
    const float* W1    = (const float*)d_in[3];
    const float* b1    = (const float*)d_in[4];
    const float* W2    = (const float*)d_in[5];
    const float* b2    = (const float*)d_in[6];
    const float* Wp    = (const float*)d_in[7];
    const float* bp    = (const float*)d_in[8];

    int N = in_sizes[0] / DF;
    int E = in_sizes[1] / 2;
    const int* src = ei;
    const int* dst = ei + E;
    int NB = (N + BNODES - 1) >> BSH;
    int quadOK = ((E & 3) == 0) && (((uintptr_t)ei & 15) == 0) && (((uintptr_t)dst & 15) == 0);

    char* ws = (char*)d_ws;
    auto alloc = [&](size_t bytes) {
        void* p = (void*)ws;
        ws += (bytes + 255) / 256 * 256;
        return p;
    };
    // zero-region: bucketCur | psums | pcnt (single memset)
    size_t zPsums = ((size_t)NB * 4 + 255) / 256 * 256;
    size_t zPcnt  = zPsums + 64 * DF * 4;
    size_t zTotal = zPcnt + 256;
    char*     zbase     = (char*)alloc(zTotal);
    int*      bucketCur = (int*)zbase;
    float*    psums     = (float*)(zbase + zPsums);
    int*      pcnt      = (int*)(zbase + zPcnt);

    float*    dinv      = (float*)alloc((size_t)N * 4);
    unsigned* bedges    = (unsigned*)alloc((size_t)NB * CAP * 4);
    int*      offs      = (int*)alloc((size_t)NB * (BNODES + 1) * 4);
    h4*       y2        = (h4*)alloc((size_t)N * DF * 2);
    h4*       h2        = (h4*)alloc((size_t)N * DF * 2);

    hipMemsetAsync(zbase, 0, zTotal, stream);

    if (quadOK) {
        int nq = E >> 2;
        int pblocks = (nq + 2047) / 2048;
        part_kernel<<<pblocks, 512, 0, stream>>>(src, dst, (const int4*)src, (const int4*)dst,
                                                 E, bedges, bucketCur, NB);
    } else {
        part_scalar_kernel<<<1024, 256, 0, stream>>>(src, dst, E, bedges, bucketCur);
    }
    sort_kernel<<<NB, 512, 0, stream>>>(bedges, bucketCur, offs, dinv, N);

    gemm_f32in<<<(N + 15) / 16, 256, 0, stream>>>((const float4*)x, (const float4*)W1, dinv,
                                                  y2, N);
    agg_kernel<<<4 * NB, 256, 0, stream>>>((const h8*)y2, bedges, offs, dinv,
                                           b1, (h8*)h2, N);
    gemm_f16in<<<(N + 15) / 16, 256, 0, stream>>>(h2, (const float4*)W2, dinv,
                                                  y2, N);
    agg_kernel<<<4 * NB, 256, 0, stream>>>((const h8*)y2, bedges, offs, dinv,
                                           b2, (h8*)h2, N);

    int waves = (N + 255) / 256;
    pool_kernel<<<(waves + 3) / 4, 256, 0, stream>>>(h2, batch, psums, pcnt, N);
    final_kernel<<<64, 64, 0, stream>>>(psums, pcnt, Wp, bp, (float*)d_out);
}